// Round 6
// baseline (621.752 us; speedup 1.0000x reference)
//
#include <hip/hip_runtime.h>
#include <hip/hip_bf16.h>
#include <math.h>

// Problem constants: B=4, S=2048, D=256, H=8, DK=32, L=4, FF=512
#define SEQ 2048
#define DIM 256
#define NH 8
#define DK 32
#define FF 512

typedef __bf16 bf16_t;
typedef bf16_t bf16x8 __attribute__((ext_vector_type(8)));
typedef bf16_t bf16x4 __attribute__((ext_vector_type(4)));
typedef float f32x4 __attribute__((ext_vector_type(4)));

// Q is pre-scaled by (1/sqrt(DK)) * log2(e); scores are then in log2 domain
// and softmax exp becomes a single v_exp_f32 (2^x).
#define QK_SCALE_LOG2 0.25503226632462494f
#if __has_builtin(__builtin_amdgcn_exp2f)
#define FAST_EXP2(x) __builtin_amdgcn_exp2f(x)
#else
#define FAST_EXP2(x) __expf((x) * 0.6931471805599453f)
#endif

// ---------------------------------------------------------------------------
// LayerNorm: one wave per row of 256 floats. OUT_BF=0 -> fp32, 1 -> bf16.
// ---------------------------------------------------------------------------
template <int OUT_BF>
__global__ __launch_bounds__(256) void ln_kernel(
    const float* __restrict__ x, const float* __restrict__ s,
    const float* __restrict__ b, float* __restrict__ outf,
    bf16_t* __restrict__ outb) {
  int wave = threadIdx.x >> 6;
  int lane = threadIdx.x & 63;
  int row = blockIdx.x * 4 + wave;
  const float* xr = x + (size_t)row * DIM + lane * 4;
  float4 xv = *(const float4*)xr;
  float sum = xv.x + xv.y + xv.z + xv.w;
  float sq = xv.x * xv.x + xv.y * xv.y + xv.z * xv.z + xv.w * xv.w;
#pragma unroll
  for (int off = 1; off < 64; off <<= 1) {
    sum += __shfl_xor(sum, off);
    sq += __shfl_xor(sq, off);
  }
  float mean = sum * (1.0f / 256.0f);
  float var = sq * (1.0f / 256.0f) - mean * mean;
  float inv = rsqrtf(var + 1e-5f);
  float4 sv = *(const float4*)(s + lane * 4);
  float4 bv = *(const float4*)(b + lane * 4);
  float4 o;
  o.x = (xv.x - mean) * inv * sv.x + bv.x;
  o.y = (xv.y - mean) * inv * sv.y + bv.y;
  o.z = (xv.z - mean) * inv * sv.z + bv.z;
  o.w = (xv.w - mean) * inv * sv.w + bv.w;
  if (OUT_BF) {
    bf16x4 ob = {(bf16_t)o.x, (bf16_t)o.y, (bf16_t)o.z, (bf16_t)o.w};
    *(bf16x4*)(outb + (size_t)row * DIM + lane * 4) = ob;
  } else {
    *(float4*)(outf + (size_t)row * DIM + lane * 4) = o;
  }
}

// ---------------------------------------------------------------------------
// All-weights transpose+convert in ONE dispatch. grid = 512 blocks:
// idx>>7 = layer; low 7 bits pick {wq,wk,wv,wo: 16 tiles each, w1: 32, w2: 32}.
// in f32 [K][N] -> out bf16 [N][K].
// ---------------------------------------------------------------------------
__global__ __launch_bounds__(256) void wtrans_all_kernel(
    const float* __restrict__ wq, const float* __restrict__ wk,
    const float* __restrict__ wv, const float* __restrict__ wo,
    const float* __restrict__ w1, const float* __restrict__ w2,
    bf16_t* __restrict__ WqT, bf16_t* __restrict__ WkT,
    bf16_t* __restrict__ WvT, bf16_t* __restrict__ WoT,
    bf16_t* __restrict__ W1T, bf16_t* __restrict__ W2T) {
  __shared__ float tile[64][65];
  int idx = blockIdx.x;
  int layer = idx >> 7;
  int r = idx & 127;
  const float* src;
  bf16_t* dst;
  int N, k0, n0;
  if (r < 64) {
    int which = r >> 4, t = r & 15;
    N = 256;
    k0 = (t & 3) * 64;
    n0 = (t >> 2) * 64;
    src = (which == 0 ? wq : which == 1 ? wk : which == 2 ? wv : wo) + (size_t)layer * 65536;
    dst = (which == 0 ? WqT : which == 1 ? WkT : which == 2 ? WvT : WoT) + (size_t)layer * 65536;
  } else if (r < 96) {
    int t = r - 64;
    N = 512;
    k0 = (t & 3) * 64;
    n0 = (t >> 2) * 64;
    src = w1 + (size_t)layer * 131072;
    dst = W1T + (size_t)layer * 131072;
  } else {
    int t = r - 96;
    N = 256;
    k0 = (t & 7) * 64;
    n0 = (t >> 3) * 64;
    src = w2 + (size_t)layer * 131072;
    dst = W2T + (size_t)layer * 131072;
  }
  int K = (r >= 96) ? 512 : 256;

  int tr = threadIdx.x >> 4;
  int tc4 = (threadIdx.x & 15) * 4;
#pragma unroll
  for (int i = 0; i < 4; i++) {
    int kl = i * 16 + tr;
    float4 v = *(const float4*)(src + (size_t)(k0 + kl) * N + n0 + tc4);
    tile[kl][tc4 + 0] = v.x; tile[kl][tc4 + 1] = v.y;
    tile[kl][tc4 + 2] = v.z; tile[kl][tc4 + 3] = v.w;
  }
  __syncthreads();
#pragma unroll
  for (int i = 0; i < 4; i++) {
    int nl = i * 16 + tr;
    bf16x4 o = {(bf16_t)tile[tc4 + 0][nl], (bf16_t)tile[tc4 + 1][nl],
                (bf16_t)tile[tc4 + 2][nl], (bf16_t)tile[tc4 + 3][nl]};
    *(bf16x4*)(dst + (size_t)(n0 + nl) * K + k0 + tc4) = o;
  }
}

// ---------------------------------------------------------------------------
// Core bf16 MFMA GEMM body: 64x64 block tile, 4 waves, 32x32 wave tile.
// ---------------------------------------------------------------------------
template <int K>
__device__ __forceinline__ void gemm_body(
    const bf16_t* __restrict__ A, const bf16_t* __restrict__ BT,
    int m_base, int n_base, int n16, int quad, f32x4 (&acc)[2][2]) {
  const bf16_t* Ap = A + (size_t)(m_base + n16) * K;
  const bf16_t* Bp = BT + (size_t)(n_base + n16) * K;
#pragma unroll
  for (int k0 = 0; k0 < K; k0 += 32) {
    bf16x8 af[2], bfr[2];
#pragma unroll
    for (int mt = 0; mt < 2; mt++)
      af[mt] = *(const bf16x8*)(Ap + (size_t)mt * 16 * K + k0 + quad * 8);
#pragma unroll
    for (int nt = 0; nt < 2; nt++)
      bfr[nt] = *(const bf16x8*)(Bp + (size_t)nt * 16 * K + k0 + quad * 8);
#pragma unroll
    for (int mt = 0; mt < 2; mt++)
#pragma unroll
      for (int nt = 0; nt < 2; nt++)
        acc[mt][nt] = __builtin_amdgcn_mfma_f32_16x16x32_bf16(
            af[mt], bfr[nt], acc[mt][nt], 0, 0, 0);
  }
}

// ---------------------------------------------------------------------------
// Generic GEMM epilogues. MODE 0: fp32 residual add. MODE 1: bf16 relu.
// ---------------------------------------------------------------------------
template <int MODE, int N, int K>
__global__ __launch_bounds__(256) void gemm_mfma_kernel(
    const bf16_t* __restrict__ A, const bf16_t* __restrict__ BT,
    const float* __restrict__ bias, const float* __restrict__ resid,
    float* __restrict__ outf, bf16_t* __restrict__ outb) {
  int w = threadIdx.x >> 6;
  int lane = threadIdx.x & 63;
  int n16 = lane & 15;
  int quad = lane >> 4;
  int m_base = blockIdx.y * 64 + (w >> 1) * 32;
  int n_base = blockIdx.x * 64 + (w & 1) * 32;
  f32x4 acc[2][2] = {};
  gemm_body<K>(A, BT, m_base, n_base, n16, quad, acc);

  float bias_v[2];
#pragma unroll
  for (int nt = 0; nt < 2; nt++) bias_v[nt] = bias[n_base + nt * 16 + n16];
#pragma unroll
  for (int mt = 0; mt < 2; mt++)
#pragma unroll
    for (int nt = 0; nt < 2; nt++) {
      int n = n_base + nt * 16 + n16;
#pragma unroll
      for (int r = 0; r < 4; r++) {
        int m = m_base + mt * 16 + quad * 4 + r;
        float val = acc[mt][nt][r] + bias_v[nt];
        if (MODE == 0) {
          size_t idx = (size_t)m * N + n;
          outf[idx] = resid[idx] + val;
        } else {
          outb[(size_t)m * N + n] = (bf16_t)fmaxf(val, 0.0f);
        }
      }
    }
}

// ---------------------------------------------------------------------------
// Fused QKV projection: grid (12, 128). blockIdx.x>>2 selects Q/K/V.
// Q scaled by QK_SCALE_LOG2 (log2-domain scores).
// ---------------------------------------------------------------------------
__global__ __launch_bounds__(256) void qkv_kernel(
    const bf16_t* __restrict__ A,
    const bf16_t* __restrict__ WqT, const bf16_t* __restrict__ WkT,
    const bf16_t* __restrict__ WvT,
    const float* __restrict__ bq, const float* __restrict__ bk,
    const float* __restrict__ bv,
    bf16_t* __restrict__ qo, bf16_t* __restrict__ ko,
    bf16_t* __restrict__ vo) {
  int which = blockIdx.x >> 2;
  int nblk = blockIdx.x & 3;
  const bf16_t* BT = (which == 0) ? WqT : (which == 1) ? WkT : WvT;
  const float* bias = (which == 0) ? bq : (which == 1) ? bk : bv;

  int w = threadIdx.x >> 6;
  int lane = threadIdx.x & 63;
  int n16 = lane & 15;
  int quad = lane >> 4;
  int m_base = blockIdx.y * 64 + (w >> 1) * 32;
  int n_base = nblk * 64 + (w & 1) * 32;
  f32x4 acc[2][2] = {};
  gemm_body<256>(A, BT, m_base, n_base, n16, quad, acc);

  float bias_v[2];
#pragma unroll
  for (int nt = 0; nt < 2; nt++) bias_v[nt] = bias[n_base + nt * 16 + n16];

#pragma unroll
  for (int mt = 0; mt < 2; mt++)
#pragma unroll
    for (int nt = 0; nt < 2; nt++) {
      int n = n_base + nt * 16 + n16;
      int hh = n >> 5, dk = n & 31;
      if (which == 2) {
        int s0 = m_base + mt * 16 + quad * 4;
        int bb = s0 >> 11, ss0 = s0 & 2047;
        bf16x4 o;
#pragma unroll
        for (int r = 0; r < 4; r++) o[r] = (bf16_t)(acc[mt][nt][r] + bias_v[nt]);
        *(bf16x4*)(vo + ((size_t)(bb * NH + hh) * DK + dk) * SEQ + ss0) = o;
      } else {
        bf16_t* dst = (which == 0) ? qo : ko;
        float sc = (which == 0) ? QK_SCALE_LOG2 : 1.0f;
#pragma unroll
        for (int r = 0; r < 4; r++) {
          int m = m_base + mt * 16 + quad * 4 + r;
          int bb = m >> 11, ss = m & 2047;
          dst[((size_t)(bb * NH + hh) * SEQ + ss) * DK + dk] =
              (bf16_t)((acc[mt][nt][r] + bias_v[nt]) * sc);
        }
      }
    }
}

// ---------------------------------------------------------------------------
// Flash attention v5: KV-split. grid (32 bh, 32 qblk, 2 kpart), 128 threads.
// Each block: 64 q-rows x 1024 keys. Since there is no max-shift, partials
// are exact partial sums: Opart = sum p*v (unnormalized, f32), lpart = sum p.
// S^T score trick (packed b64 P stores), 32 q/wave ILP, double-buffered P,
// unroll 2. Zero barriers / zero loop cross-lane ops.
// ---------------------------------------------------------------------------
__global__ __launch_bounds__(128) void flash5_kernel(
    const bf16_t* __restrict__ Q, const bf16_t* __restrict__ K,
    const bf16_t* __restrict__ VT, float* __restrict__ Opart,
    float* __restrict__ lpart) {
  __shared__ __align__(16) bf16_t Plds[2][2][32][72];  // [buf][wave][q][key]
  int bh = blockIdx.x;
  int q0 = blockIdx.y * 64;
  int part = blockIdx.z;
  int w = threadIdx.x >> 6;
  int lane = threadIdx.x & 63;
  int n16 = lane & 15;
  int quad = lane >> 4;

  const bf16_t* Qb = Q + (size_t)bh * SEQ * DK;
  const bf16_t* Kb = K + (size_t)bh * SEQ * DK;
  const bf16_t* Vb = VT + (size_t)bh * DK * SEQ;
  int qr0 = q0 + w * 32;

  bf16x8 qfrag[2];
#pragma unroll
  for (int qg = 0; qg < 2; qg++)
    qfrag[qg] = *(const bf16x8*)(Qb + (size_t)(qr0 + qg * 16 + n16) * DK + quad * 8);

  f32x4 oacc[2][2] = {};
  float lsum[2] = {0.0f, 0.0f};
  int kstart = part * 1024;

#pragma unroll 2
  for (int kk = 0; kk < 1024; kk += 64) {
    int kb0 = kstart + kk;
    int buf = (kk >> 6) & 1;
    bf16x8 kf[4];
#pragma unroll
    for (int t = 0; t < 4; t++)
      kf[t] = *(const bf16x8*)(Kb + (size_t)(kb0 + t * 16 + n16) * DK + quad * 8);
    bf16x8 vf[2][2];
#pragma unroll
    for (int c = 0; c < 2; c++) {
      vf[c][0] = *(const bf16x8*)(Vb + (size_t)n16 * SEQ + kb0 + c * 32 + quad * 8);
      vf[c][1] = *(const bf16x8*)(Vb + (size_t)(16 + n16) * SEQ + kb0 + c * 32 + quad * 8);
    }
#pragma unroll
    for (int qg = 0; qg < 2; qg++) {
#pragma unroll
      for (int t = 0; t < 4; t++) {
        f32x4 sc = __builtin_amdgcn_mfma_f32_16x16x32_bf16(
            kf[t], qfrag[qg], (f32x4){0.f, 0.f, 0.f, 0.f}, 0, 0, 0);
        bf16x4 pf;
#pragma unroll
        for (int r = 0; r < 4; r++) {
          float p = FAST_EXP2(sc[r]);
          lsum[qg] += p;
          pf[r] = (bf16_t)p;
        }
        *(bf16x4*)&Plds[buf][w][qg * 16 + n16][t * 16 + quad * 4] = pf;
      }
    }
#pragma unroll
    for (int qg = 0; qg < 2; qg++)
#pragma unroll
      for (int c = 0; c < 2; c++) {
        bf16x8 pf8 = *(const bf16x8*)&Plds[buf][w][qg * 16 + n16][c * 32 + quad * 8];
        oacc[qg][0] = __builtin_amdgcn_mfma_f32_16x16x32_bf16(pf8, vf[c][0], oacc[qg][0], 0, 0, 0);
        oacc[qg][1] = __builtin_amdgcn_mfma_f32_16x16x32_bf16(pf8, vf[c][1], oacc[qg][1], 0, 0, 0);
      }
  }

  // epilogue: reduce l across quads; write unnormalized partials
#pragma unroll
  for (int qg = 0; qg < 2; qg++) {
    lsum[qg] += __shfl_xor(lsum[qg], 16);
    lsum[qg] += __shfl_xor(lsum[qg], 32);
  }
  size_t rowbase = (size_t)part * 65536 + (size_t)bh * SEQ;
#pragma unroll
  for (int qg = 0; qg < 2; qg++) {
    if (quad == 0) lpart[rowbase + qr0 + qg * 16 + n16] = lsum[qg];
#pragma unroll
    for (int r = 0; r < 4; r++) {
      int qrow = qr0 + qg * 16 + quad * 4 + r;
      float* op = Opart + (rowbase + qrow) * 32;
      op[n16] = oacc[qg][0][r];
      op[16 + n16] = oacc[qg][1][r];
    }
  }
}

// ---------------------------------------------------------------------------
// Combine KV-split partials: O = (O0+O1)/(l0+l1) -> bf16 [B,S,D].
// grid 8192 x 256 threads; one thread per (row, dk).
// ---------------------------------------------------------------------------
__global__ __launch_bounds__(256) void combine_kernel(
    const float* __restrict__ Opart, const float* __restrict__ lpart,
    bf16_t* __restrict__ OB) {
  int g = blockIdx.x * 256 + threadIdx.x;
  int row = g >> 5;   // bh*SEQ + s
  int dk = g & 31;
  float o = Opart[(size_t)row * 32 + dk] + Opart[(size_t)(65536 + row) * 32 + dk];
  float l = lpart[row] + lpart[65536 + row];
  int bh = row >> 11, s = row & 2047;
  int bb = bh >> 3, hh = bh & 7;
  OB[((size_t)(bb * SEQ + s)) * DIM + hh * DK + dk] = (bf16_t)(o / l);
}

// ---------------------------------------------------------------------------
extern "C" void kernel_launch(void* const* d_in, const int* in_sizes, int n_in,
                              void* d_out, int out_size, void* d_ws, size_t ws_size,
                              hipStream_t stream) {
  const float* x     = (const float*)d_in[0];
  const float* ln0_s = (const float*)d_in[1];
  const float* ln0_b = (const float*)d_in[2];
  const float* ln1_s = (const float*)d_in[3];
  const float* ln1_b = (const float*)d_in[4];
  const float* ln2_s = (const float*)d_in[5];
  const float* ln2_b = (const float*)d_in[6];
  const float* wq = (const float*)d_in[7];
  const float* bq = (const float*)d_in[8];
  const float* wk = (const float*)d_in[9];
  const float* bk = (const float*)d_in[10];
  const float* wv = (const float*)d_in[11];
  const float* bv = (const float*)d_in[12];
  const float* wo = (const float*)d_in[13];
  const float* bo = (const float*)d_in[14];
  const float* w1 = (const float*)d_in[15];
  const float* b1 = (const float*)d_in[16];
  const float* w2 = (const float*)d_in[17];
  const float* b2 = (const float*)d_in[18];

  float* out = (float*)d_out;  // h (fp32 residual stream) lives here
  const size_t ACT = (size_t)8192 * DIM;  // 2,097,152

  bf16_t* wsb = (bf16_t*)d_ws;
  bf16_t* x2b = wsb;                 // ACT
  bf16_t* obf = x2b + ACT;           // ACT
  bf16_t* qbf = obf + ACT;           // ACT
  bf16_t* kbf = qbf + ACT;           // ACT
  bf16_t* vbf = kbf + ACT;           // ACT (transposed [B,H,DK,S])
  bf16_t* h1b = vbf + ACT;           // 2*ACT (8192 x 512)
  bf16_t* WqT = h1b + 2 * ACT;       // 4 x 65536
  bf16_t* WkT = WqT + 4 * 65536;
  bf16_t* WvT = WkT + 4 * 65536;
  bf16_t* WoT = WvT + 4 * 65536;
  bf16_t* W1T = WoT + 4 * 65536;     // 4 x 131072
  bf16_t* W2T = W1T + 4 * 131072;    // 4 x 131072
  float* Opart = (float*)(W2T + 4 * 131072);  // 2 x 65536 x 32 f32 (16.8 MB)
  float* lpart = Opart + (size_t)2 * 65536 * 32;  // 2 x 65536 f32

  dim3 blk(256);
  dim3 blkF(128);
  dim3 gLN(2048);
  dim3 gG256(4, 128);
  dim3 gG512(8, 128);
  dim3 gQKV(12, 128);
  dim3 gAtt(32, 32, 2);
  dim3 gComb(8192);

  wtrans_all_kernel<<<dim3(512), blk, 0, stream>>>(wq, wk, wv, wo, w1, w2,
                                                   WqT, WkT, WvT, WoT, W1T, W2T);

  // h = LN(x, ln0) -> fp32 d_out
  ln_kernel<0><<<gLN, blk, 0, stream>>>(x, ln0_s, ln0_b, out, nullptr);

  for (int l = 0; l < 4; l++) {
    bf16_t* WqTl = WqT + (size_t)l * 65536;
    bf16_t* WkTl = WkT + (size_t)l * 65536;
    bf16_t* WvTl = WvT + (size_t)l * 65536;
    bf16_t* WoTl = WoT + (size_t)l * 65536;
    bf16_t* W1Tl = W1T + (size_t)l * 131072;
    bf16_t* W2Tl = W2T + (size_t)l * 131072;

    // x2 = LN(h, ln1) -> bf16
    ln_kernel<1><<<gLN, blk, 0, stream>>>(out, ln1_s + l * DIM, ln1_b + l * DIM, nullptr, x2b);
    // fused q,k,v projections
    qkv_kernel<<<gQKV, blk, 0, stream>>>(x2b, WqTl, WkTl, WvTl,
                                         bq + l * DIM, bk + l * DIM, bv + l * DIM,
                                         qbf, kbf, vbf);
    // attention: KV-split partials, then combine
    flash5_kernel<<<gAtt, blkF, 0, stream>>>(qbf, kbf, vbf, Opart, lpart);
    combine_kernel<<<gComb, blk, 0, stream>>>(Opart, lpart, obf);
    // h = h + o @ Wo + bo
    gemm_mfma_kernel<0, 256, 256><<<gG256, blk, 0, stream>>>(obf, WoTl, bo + l * DIM, out, out, nullptr);
    // x2 = LN(h, ln2) -> bf16
    ln_kernel<1><<<gLN, blk, 0, stream>>>(out, ln2_s + l * DIM, ln2_b + l * DIM, nullptr, x2b);
    // h1 = relu(x2 @ W1 + b1) -> bf16
    gemm_mfma_kernel<1, 512, 256><<<gG512, blk, 0, stream>>>(x2b, W1Tl, b1 + l * FF, nullptr, nullptr, h1b);
    // h = h + h1 @ W2 + b2
    gemm_mfma_kernel<0, 256, 512><<<gG256, blk, 0, stream>>>(h1b, W2Tl, b2 + l * DIM, out, out, nullptr);
  }
}

// Round 7
// 468.772 us; speedup vs baseline: 1.3263x; 1.3263x over previous
//
#include <hip/hip_runtime.h>
#include <hip/hip_bf16.h>
#include <math.h>

// Problem constants: B=4, S=2048, D=256, H=8, DK=32, L=4, FF=512
#define SEQ 2048
#define DIM 256
#define NH 8
#define DK 32
#define FF 512

typedef __bf16 bf16_t;
typedef bf16_t bf16x8 __attribute__((ext_vector_type(8)));
typedef bf16_t bf16x4 __attribute__((ext_vector_type(4)));
typedef float f32x4 __attribute__((ext_vector_type(4)));

// Q pre-scaled by (1/sqrt(DK)) * log2(e); softmax exp becomes v_exp_f32 (2^x).
#define QK_SCALE_LOG2 0.25503226632462494f
#if __has_builtin(__builtin_amdgcn_exp2f)
#define FAST_EXP2(x) __builtin_amdgcn_exp2f(x)
#else
#define FAST_EXP2(x) __expf((x) * 0.6931471805599453f)
#endif

// ---------------------------------------------------------------------------
// LayerNorm: one wave per row of 256 floats. OUT_BF=0 -> fp32, 1 -> bf16.
// ---------------------------------------------------------------------------
template <int OUT_BF>
__global__ __launch_bounds__(256) void ln_kernel(
    const float* __restrict__ x, const float* __restrict__ s,
    const float* __restrict__ b, float* __restrict__ outf,
    bf16_t* __restrict__ outb) {
  int wave = threadIdx.x >> 6;
  int lane = threadIdx.x & 63;
  int row = blockIdx.x * 4 + wave;
  const float* xr = x + (size_t)row * DIM + lane * 4;
  float4 xv = *(const float4*)xr;
  float sum = xv.x + xv.y + xv.z + xv.w;
  float sq = xv.x * xv.x + xv.y * xv.y + xv.z * xv.z + xv.w * xv.w;
#pragma unroll
  for (int off = 1; off < 64; off <<= 1) {
    sum += __shfl_xor(sum, off);
    sq += __shfl_xor(sq, off);
  }
  float mean = sum * (1.0f / 256.0f);
  float var = sq * (1.0f / 256.0f) - mean * mean;
  float inv = rsqrtf(var + 1e-5f);
  float4 sv = *(const float4*)(s + lane * 4);
  float4 bv = *(const float4*)(b + lane * 4);
  float4 o;
  o.x = (xv.x - mean) * inv * sv.x + bv.x;
  o.y = (xv.y - mean) * inv * sv.y + bv.y;
  o.z = (xv.z - mean) * inv * sv.z + bv.z;
  o.w = (xv.w - mean) * inv * sv.w + bv.w;
  if (OUT_BF) {
    bf16x4 ob = {(bf16_t)o.x, (bf16_t)o.y, (bf16_t)o.z, (bf16_t)o.w};
    *(bf16x4*)(outb + (size_t)row * DIM + lane * 4) = ob;
  } else {
    *(float4*)(outf + (size_t)row * DIM + lane * 4) = o;
  }
}

// ---------------------------------------------------------------------------
// All-weights transpose+convert in ONE dispatch (512 blocks).
// in f32 [K][N] -> out bf16 [N][K].
// ---------------------------------------------------------------------------
__global__ __launch_bounds__(256) void wtrans_all_kernel(
    const float* __restrict__ wq, const float* __restrict__ wk,
    const float* __restrict__ wv, const float* __restrict__ wo,
    const float* __restrict__ w1, const float* __restrict__ w2,
    bf16_t* __restrict__ WqT, bf16_t* __restrict__ WkT,
    bf16_t* __restrict__ WvT, bf16_t* __restrict__ WoT,
    bf16_t* __restrict__ W1T, bf16_t* __restrict__ W2T) {
  __shared__ float tile[64][65];
  int idx = blockIdx.x;
  int layer = idx >> 7;
  int r = idx & 127;
  const float* src;
  bf16_t* dst;
  int N, k0, n0;
  if (r < 64) {
    int which = r >> 4, t = r & 15;
    N = 256;
    k0 = (t & 3) * 64;
    n0 = (t >> 2) * 64;
    src = (which == 0 ? wq : which == 1 ? wk : which == 2 ? wv : wo) + (size_t)layer * 65536;
    dst = (which == 0 ? WqT : which == 1 ? WkT : which == 2 ? WvT : WoT) + (size_t)layer * 65536;
  } else if (r < 96) {
    int t = r - 64;
    N = 512;
    k0 = (t & 3) * 64;
    n0 = (t >> 2) * 64;
    src = w1 + (size_t)layer * 131072;
    dst = W1T + (size_t)layer * 131072;
  } else {
    int t = r - 96;
    N = 256;
    k0 = (t & 7) * 64;
    n0 = (t >> 3) * 64;
    src = w2 + (size_t)layer * 131072;
    dst = W2T + (size_t)layer * 131072;
  }
  int K = (r >= 96) ? 512 : 256;

  int tr = threadIdx.x >> 4;
  int tc4 = (threadIdx.x & 15) * 4;
#pragma unroll
  for (int i = 0; i < 4; i++) {
    int kl = i * 16 + tr;
    float4 v = *(const float4*)(src + (size_t)(k0 + kl) * N + n0 + tc4);
    tile[kl][tc4 + 0] = v.x; tile[kl][tc4 + 1] = v.y;
    tile[kl][tc4 + 2] = v.z; tile[kl][tc4 + 3] = v.w;
  }
  __syncthreads();
#pragma unroll
  for (int i = 0; i < 4; i++) {
    int nl = i * 16 + tr;
    bf16x4 o = {(bf16_t)tile[tc4 + 0][nl], (bf16_t)tile[tc4 + 1][nl],
                (bf16_t)tile[tc4 + 2][nl], (bf16_t)tile[tc4 + 3][nl]};
    *(bf16x4*)(dst + (size_t)(n0 + nl) * K + k0 + tc4) = o;
  }
}

// ---------------------------------------------------------------------------
// Async-staged bf16 MFMA GEMM core (m97 pattern scaled to 64x64/BK=64).
// LDS tiles are stored with an XOR chunk swizzle applied on the SOURCE side
// (global_load_lds dest is lane-sequential): LDS[m][cd] holds logical chunk
// cd ^ (m&7), so ds_read_b128 fragment reads are bank-conflict-free.
// ---------------------------------------------------------------------------
__device__ __forceinline__ void stage_tile(const bf16_t* __restrict__ src,
                                           bf16_t* dst, int tid, int ldk, int k0) {
#pragma unroll
  for (int u = 0; u < 2; u++) {
    int i = u * 256 + tid;
    int m = i >> 3, cd = i & 7, cs = cd ^ (m & 7);
    const bf16_t* g = src + (size_t)m * ldk + k0 + cs * 8;
    __builtin_amdgcn_global_load_lds(
        (const __attribute__((address_space(1))) unsigned int*)g,
        (__attribute__((address_space(3))) unsigned int*)(dst + i * 8),
        16, 0, 0);
  }
}

template <int K>
__device__ __forceinline__ void gemm7_body(
    const bf16_t* __restrict__ A, const bf16_t* __restrict__ BT,
    int m0, int n0, int tid, bf16_t* As, bf16_t* Bs, f32x4 (&acc)[2][2]) {
  const int lane = tid & 63;
  const int n16 = lane & 15, quad = lane >> 4;
  const int w = tid >> 6;
  const int mw = (w >> 1) * 32, nw = (w & 1) * 32;
  const int sw = n16 & 7;
  const bf16_t* Arow = A + (size_t)m0 * K;
  const bf16_t* Brow = BT + (size_t)n0 * K;

  stage_tile(Arow, As, tid, K, 0);
  stage_tile(Brow, Bs, tid, K, 0);
  __syncthreads();

  const int steps = K / 64;
#pragma unroll
  for (int s = 0; s < steps; s++) {
    int buf = s & 1;
    if (s + 1 < steps) {
      stage_tile(Arow, As + (buf ^ 1) * 4096, tid, K, (s + 1) * 64);
      stage_tile(Brow, Bs + (buf ^ 1) * 4096, tid, K, (s + 1) * 64);
    }
    const bf16_t* a = As + buf * 4096;
    const bf16_t* b = Bs + buf * 4096;
    bf16x8 af[2][2], bfv[2][2];
#pragma unroll
    for (int t = 0; t < 2; t++)
#pragma unroll
      for (int ks = 0; ks < 2; ks++) {
        int cd = (ks * 4 + quad) ^ sw;
        af[t][ks] = *(const bf16x8*)(a + (mw + t * 16 + n16) * 64 + cd * 8);
        bfv[t][ks] = *(const bf16x8*)(b + (nw + t * 16 + n16) * 64 + cd * 8);
      }
#pragma unroll
    for (int ks = 0; ks < 2; ks++)
#pragma unroll
      for (int mt = 0; mt < 2; mt++)
#pragma unroll
        for (int nt = 0; nt < 2; nt++)
          acc[mt][nt] = __builtin_amdgcn_mfma_f32_16x16x32_bf16(
              af[mt][ks], bfv[nt][ks], acc[mt][nt], 0, 0, 0);
    __syncthreads();
  }
}

// ---------------------------------------------------------------------------
// Generic GEMM. MODE 0: fp32 residual add. MODE 1: bf16 relu.
// ---------------------------------------------------------------------------
template <int MODE, int N, int K>
__global__ __launch_bounds__(256) void gemm7_kernel(
    const bf16_t* __restrict__ A, const bf16_t* __restrict__ BT,
    const float* __restrict__ bias, const float* __restrict__ resid,
    float* __restrict__ outf, bf16_t* __restrict__ outb) {
  __shared__ __align__(16) bf16_t As[2 * 4096];
  __shared__ __align__(16) bf16_t Bs[2 * 4096];
  int tid = threadIdx.x;
  int lane = tid & 63;
  int n16 = lane & 15, quad = lane >> 4;
  int w = tid >> 6;
  int m0 = blockIdx.y * 64, n0 = blockIdx.x * 64;
  f32x4 acc[2][2] = {};
  gemm7_body<K>(A, BT, m0, n0, tid, As, Bs, acc);

  int m_base = m0 + (w >> 1) * 32;
  int n_base = n0 + (w & 1) * 32;
  float bias_v[2];
#pragma unroll
  for (int nt = 0; nt < 2; nt++) bias_v[nt] = bias[n_base + nt * 16 + n16];
#pragma unroll
  for (int mt = 0; mt < 2; mt++)
#pragma unroll
    for (int nt = 0; nt < 2; nt++) {
      int n = n_base + nt * 16 + n16;
#pragma unroll
      for (int r = 0; r < 4; r++) {
        int m = m_base + mt * 16 + quad * 4 + r;
        float val = acc[mt][nt][r] + bias_v[nt];
        if (MODE == 0) {
          size_t idx = (size_t)m * N + n;
          outf[idx] = resid[idx] + val;
        } else {
          outb[(size_t)m * N + n] = (bf16_t)fmaxf(val, 0.0f);
        }
      }
    }
}

// ---------------------------------------------------------------------------
// Fused QKV projection on the staged body: grid (12, 128), bx>>2 picks Q/K/V.
// ---------------------------------------------------------------------------
__global__ __launch_bounds__(256) void qkv7_kernel(
    const bf16_t* __restrict__ A,
    const bf16_t* __restrict__ WqT, const bf16_t* __restrict__ WkT,
    const bf16_t* __restrict__ WvT,
    const float* __restrict__ bq, const float* __restrict__ bk,
    const float* __restrict__ bv,
    bf16_t* __restrict__ qo, bf16_t* __restrict__ ko,
    bf16_t* __restrict__ vo) {
  __shared__ __align__(16) bf16_t As[2 * 4096];
  __shared__ __align__(16) bf16_t Bs[2 * 4096];
  int which = blockIdx.x >> 2;
  int nblk = blockIdx.x & 3;
  const bf16_t* BT = (which == 0) ? WqT : (which == 1) ? WkT : WvT;
  const float* bias = (which == 0) ? bq : (which == 1) ? bk : bv;

  int tid = threadIdx.x;
  int lane = tid & 63;
  int n16 = lane & 15, quad = lane >> 4;
  int w = tid >> 6;
  int m0 = blockIdx.y * 64, n0 = nblk * 64;
  f32x4 acc[2][2] = {};
  gemm7_body<256>(A, BT, m0, n0, tid, As, Bs, acc);

  int m_base = m0 + (w >> 1) * 32;
  int n_base = n0 + (w & 1) * 32;
  float bias_v[2];
#pragma unroll
  for (int nt = 0; nt < 2; nt++) bias_v[nt] = bias[n_base + nt * 16 + n16];

#pragma unroll
  for (int mt = 0; mt < 2; mt++)
#pragma unroll
    for (int nt = 0; nt < 2; nt++) {
      int n = n_base + nt * 16 + n16;
      int hh = n >> 5, dk = n & 31;
      if (which == 2) {
        int s0 = m_base + mt * 16 + quad * 4;
        int bb = s0 >> 11, ss0 = s0 & 2047;
        bf16x4 o;
#pragma unroll
        for (int r = 0; r < 4; r++) o[r] = (bf16_t)(acc[mt][nt][r] + bias_v[nt]);
        *(bf16x4*)(vo + ((size_t)(bb * NH + hh) * DK + dk) * SEQ + ss0) = o;
      } else {
        bf16_t* dst = (which == 0) ? qo : ko;
        float sc = (which == 0) ? QK_SCALE_LOG2 : 1.0f;
#pragma unroll
        for (int r = 0; r < 4; r++) {
          int m = m_base + mt * 16 + quad * 4 + r;
          int bb = m >> 11, ss = m & 2047;
          dst[((size_t)(bb * NH + hh) * SEQ + ss) * DK + dk] =
              (bf16_t)((acc[mt][nt][r] + bias_v[nt]) * sc);
        }
      }
    }
}

// ---------------------------------------------------------------------------
// Flash attention v6: 32 q/wave, S^T score trick, double-buffered P, unroll 2,
// row-sums l via ones-MFMA (B=ones with A=P gives D rows in the SAME C-layout
// as the O accumulator -> zero cross-lane normalization). No barriers, no
// cross-lane in loop. grid (32 bh, 32 qblk), 128 threads.
// ---------------------------------------------------------------------------
__global__ __launch_bounds__(128) void flash6_kernel(
    const bf16_t* __restrict__ Q, const bf16_t* __restrict__ K,
    const bf16_t* __restrict__ VT, bf16_t* __restrict__ OB) {
  __shared__ __align__(16) bf16_t Plds[2][2][32][72];  // [buf][wave][q][key]
  int bh = blockIdx.x;
  int q0 = blockIdx.y * 64;
  int w = threadIdx.x >> 6;
  int lane = threadIdx.x & 63;
  int n16 = lane & 15;
  int quad = lane >> 4;

  const bf16_t* Qb = Q + (size_t)bh * SEQ * DK;
  const bf16_t* Kb = K + (size_t)bh * SEQ * DK;
  const bf16_t* Vb = VT + (size_t)bh * DK * SEQ;
  int qr0 = q0 + w * 32;

  bf16x8 qfrag[2];
#pragma unroll
  for (int qg = 0; qg < 2; qg++)
    qfrag[qg] = *(const bf16x8*)(Qb + (size_t)(qr0 + qg * 16 + n16) * DK + quad * 8);

  bf16_t one = (bf16_t)1.0f;
  bf16x8 ones = {one, one, one, one, one, one, one, one};

  f32x4 oacc[2][2] = {};
  f32x4 lacc[2] = {};

#pragma unroll 2
  for (int kb0 = 0; kb0 < SEQ; kb0 += 64) {
    int buf = (kb0 >> 6) & 1;
    bf16x8 kf[4];
#pragma unroll
    for (int t = 0; t < 4; t++)
      kf[t] = *(const bf16x8*)(Kb + (size_t)(kb0 + t * 16 + n16) * DK + quad * 8);
    bf16x8 vf[2][2];
#pragma unroll
    for (int c = 0; c < 2; c++) {
      vf[c][0] = *(const bf16x8*)(Vb + (size_t)n16 * SEQ + kb0 + c * 32 + quad * 8);
      vf[c][1] = *(const bf16x8*)(Vb + (size_t)(16 + n16) * SEQ + kb0 + c * 32 + quad * 8);
    }
#pragma unroll
    for (int qg = 0; qg < 2; qg++) {
#pragma unroll
      for (int t = 0; t < 4; t++) {
        f32x4 sc = __builtin_amdgcn_mfma_f32_16x16x32_bf16(
            kf[t], qfrag[qg], (f32x4){0.f, 0.f, 0.f, 0.f}, 0, 0, 0);
        bf16x4 pf;
#pragma unroll
        for (int r = 0; r < 4; r++) pf[r] = (bf16_t)FAST_EXP2(sc[r]);
        *(bf16x4*)&Plds[buf][w][qg * 16 + n16][t * 16 + quad * 4] = pf;
      }
    }
#pragma unroll
    for (int qg = 0; qg < 2; qg++)
#pragma unroll
      for (int c = 0; c < 2; c++) {
        bf16x8 pf8 = *(const bf16x8*)&Plds[buf][w][qg * 16 + n16][c * 32 + quad * 8];
        lacc[qg] = __builtin_amdgcn_mfma_f32_16x16x32_bf16(pf8, ones, lacc[qg], 0, 0, 0);
        oacc[qg][0] = __builtin_amdgcn_mfma_f32_16x16x32_bf16(pf8, vf[c][0], oacc[qg][0], 0, 0, 0);
        oacc[qg][1] = __builtin_amdgcn_mfma_f32_16x16x32_bf16(pf8, vf[c][1], oacc[qg][1], 0, 0, 0);
      }
  }

  int bb = bh >> 3, hh = bh & 7;
#pragma unroll
  for (int qg = 0; qg < 2; qg++)
#pragma unroll
    for (int r = 0; r < 4; r++) {
      float linv = 1.0f / lacc[qg][r];
      int row = qr0 + qg * 16 + quad * 4 + r;
      bf16_t* op = OB + ((size_t)(bb * SEQ + row)) * DIM + hh * DK;
      op[n16] = (bf16_t)(oacc[qg][0][r] * linv);
      op[16 + n16] = (bf16_t)(oacc[qg][1][r] * linv);
    }
}

// ---------------------------------------------------------------------------
extern "C" void kernel_launch(void* const* d_in, const int* in_sizes, int n_in,
                              void* d_out, int out_size, void* d_ws, size_t ws_size,
                              hipStream_t stream) {
  const float* x     = (const float*)d_in[0];
  const float* ln0_s = (const float*)d_in[1];
  const float* ln0_b = (const float*)d_in[2];
  const float* ln1_s = (const float*)d_in[3];
  const float* ln1_b = (const float*)d_in[4];
  const float* ln2_s = (const float*)d_in[5];
  const float* ln2_b = (const float*)d_in[6];
  const float* wq = (const float*)d_in[7];
  const float* bq = (const float*)d_in[8];
  const float* wk = (const float*)d_in[9];
  const float* bk = (const float*)d_in[10];
  const float* wv = (const float*)d_in[11];
  const float* bv = (const float*)d_in[12];
  const float* wo = (const float*)d_in[13];
  const float* bo = (const float*)d_in[14];
  const float* w1 = (const float*)d_in[15];
  const float* b1 = (const float*)d_in[16];
  const float* w2 = (const float*)d_in[17];
  const float* b2 = (const float*)d_in[18];

  float* out = (float*)d_out;  // h (fp32 residual stream) lives here
  const size_t ACT = (size_t)8192 * DIM;  // 2,097,152

  bf16_t* wsb = (bf16_t*)d_ws;
  bf16_t* x2b = wsb;                 // ACT
  bf16_t* obf = x2b + ACT;           // ACT
  bf16_t* qbf = obf + ACT;           // ACT
  bf16_t* kbf = qbf + ACT;           // ACT
  bf16_t* vbf = kbf + ACT;           // ACT (transposed [B,H,DK,S])
  bf16_t* h1b = vbf + ACT;           // 2*ACT (8192 x 512)
  bf16_t* WqT = h1b + 2 * ACT;       // 4 x 65536
  bf16_t* WkT = WqT + 4 * 65536;
  bf16_t* WvT = WkT + 4 * 65536;
  bf16_t* WoT = WvT + 4 * 65536;
  bf16_t* W1T = WoT + 4 * 65536;     // 4 x 131072
  bf16_t* W2T = W1T + 4 * 131072;    // 4 x 131072

  dim3 blk(256);
  dim3 blkF(128);
  dim3 gLN(2048);
  dim3 gG256(4, 128);
  dim3 gG512(8, 128);
  dim3 gQKV(12, 128);
  dim3 gAtt(32, 32);

  wtrans_all_kernel<<<dim3(512), blk, 0, stream>>>(wq, wk, wv, wo, w1, w2,
                                                   WqT, WkT, WvT, WoT, W1T, W2T);

  // h = LN(x, ln0) -> fp32 d_out
  ln_kernel<0><<<gLN, blk, 0, stream>>>(x, ln0_s, ln0_b, out, nullptr);

  for (int l = 0; l < 4; l++) {
    bf16_t* WqTl = WqT + (size_t)l * 65536;
    bf16_t* WkTl = WkT + (size_t)l * 65536;
    bf16_t* WvTl = WvT + (size_t)l * 65536;
    bf16_t* WoTl = WoT + (size_t)l * 65536;
    bf16_t* W1Tl = W1T + (size_t)l * 131072;
    bf16_t* W2Tl = W2T + (size_t)l * 131072;

    // x2 = LN(h, ln1) -> bf16
    ln_kernel<1><<<gLN, blk, 0, stream>>>(out, ln1_s + l * DIM, ln1_b + l * DIM, nullptr, x2b);
    // fused q,k,v projections (async-staged GEMM)
    qkv7_kernel<<<gQKV, blk, 0, stream>>>(x2b, WqTl, WkTl, WvTl,
                                          bq + l * DIM, bk + l * DIM, bv + l * DIM,
                                          qbf, kbf, vbf);
    // attention
    flash6_kernel<<<gAtt, blkF, 0, stream>>>(qbf, kbf, vbf, obf);
    // h = h + o @ Wo + bo
    gemm7_kernel<0, 256, 256><<<gG256, blk, 0, stream>>>(obf, WoTl, bo + l * DIM, out, out, nullptr);
    // x2 = LN(h, ln2) -> bf16
    ln_kernel<1><<<gLN, blk, 0, stream>>>(out, ln2_s + l * DIM, ln2_b + l * DIM, nullptr, x2b);
    // h1 = relu(x2 @ W1 + b1) -> bf16
    gemm7_kernel<1, 512, 256><<<gG512, blk, 0, stream>>>(x2b, W1Tl, b1 + l * FF, nullptr, nullptr, h1b);
    // h = h + h1 @ W2 + b2
    gemm7_kernel<0, 256, 512><<<gG256, blk, 0, stream>>>(h1b, W2Tl, b2 + l * DIM, out, out, nullptr);
  }
}

// Round 8
// 468.230 us; speedup vs baseline: 1.3279x; 1.0012x over previous
//
#include <hip/hip_runtime.h>
#include <hip/hip_bf16.h>
#include <math.h>

// Problem constants: B=4, S=2048, D=256, H=8, DK=32, L=4, FF=512
#define SEQ 2048
#define DIM 256
#define NH 8
#define DK 32
#define FF 512

typedef __bf16 bf16_t;
typedef bf16_t bf16x8 __attribute__((ext_vector_type(8)));
typedef bf16_t bf16x4 __attribute__((ext_vector_type(4)));
typedef float f32x4 __attribute__((ext_vector_type(4)));

// Q pre-scaled by (1/sqrt(DK)) * log2(e); softmax exp becomes v_exp_f32 (2^x).
#define QK_SCALE_LOG2 0.25503226632462494f
#if __has_builtin(__builtin_amdgcn_exp2f)
#define FAST_EXP2(x) __builtin_amdgcn_exp2f(x)
#else
#define FAST_EXP2(x) __expf((x) * 0.6931471805599453f)
#endif

// ---------------------------------------------------------------------------
// LayerNorm: one wave per row of 256 floats. OUT_BF=0 -> fp32, 1 -> bf16.
// ---------------------------------------------------------------------------
template <int OUT_BF>
__global__ __launch_bounds__(256) void ln_kernel(
    const float* __restrict__ x, const float* __restrict__ s,
    const float* __restrict__ b, float* __restrict__ outf,
    bf16_t* __restrict__ outb) {
  int wave = threadIdx.x >> 6;
  int lane = threadIdx.x & 63;
  int row = blockIdx.x * 4 + wave;
  const float* xr = x + (size_t)row * DIM + lane * 4;
  float4 xv = *(const float4*)xr;
  float sum = xv.x + xv.y + xv.z + xv.w;
  float sq = xv.x * xv.x + xv.y * xv.y + xv.z * xv.z + xv.w * xv.w;
#pragma unroll
  for (int off = 1; off < 64; off <<= 1) {
    sum += __shfl_xor(sum, off);
    sq += __shfl_xor(sq, off);
  }
  float mean = sum * (1.0f / 256.0f);
  float var = sq * (1.0f / 256.0f) - mean * mean;
  float inv = rsqrtf(var + 1e-5f);
  float4 sv = *(const float4*)(s + lane * 4);
  float4 bv = *(const float4*)(b + lane * 4);
  float4 o;
  o.x = (xv.x - mean) * inv * sv.x + bv.x;
  o.y = (xv.y - mean) * inv * sv.y + bv.y;
  o.z = (xv.z - mean) * inv * sv.z + bv.z;
  o.w = (xv.w - mean) * inv * sv.w + bv.w;
  if (OUT_BF) {
    bf16x4 ob = {(bf16_t)o.x, (bf16_t)o.y, (bf16_t)o.z, (bf16_t)o.w};
    *(bf16x4*)(outb + (size_t)row * DIM + lane * 4) = ob;
  } else {
    *(float4*)(outf + (size_t)row * DIM + lane * 4) = o;
  }
}

// ---------------------------------------------------------------------------
// All-weights transpose+convert in ONE dispatch (512 blocks).
// in f32 [K][N] -> out bf16 [N][K].
// ---------------------------------------------------------------------------
__global__ __launch_bounds__(256) void wtrans_all_kernel(
    const float* __restrict__ wq, const float* __restrict__ wk,
    const float* __restrict__ wv, const float* __restrict__ wo,
    const float* __restrict__ w1, const float* __restrict__ w2,
    bf16_t* __restrict__ WqT, bf16_t* __restrict__ WkT,
    bf16_t* __restrict__ WvT, bf16_t* __restrict__ WoT,
    bf16_t* __restrict__ W1T, bf16_t* __restrict__ W2T) {
  __shared__ float tile[64][65];
  int idx = blockIdx.x;
  int layer = idx >> 7;
  int r = idx & 127;
  const float* src;
  bf16_t* dst;
  int N, k0, n0;
  if (r < 64) {
    int which = r >> 4, t = r & 15;
    N = 256;
    k0 = (t & 3) * 64;
    n0 = (t >> 2) * 64;
    src = (which == 0 ? wq : which == 1 ? wk : which == 2 ? wv : wo) + (size_t)layer * 65536;
    dst = (which == 0 ? WqT : which == 1 ? WkT : which == 2 ? WvT : WoT) + (size_t)layer * 65536;
  } else if (r < 96) {
    int t = r - 64;
    N = 512;
    k0 = (t & 3) * 64;
    n0 = (t >> 2) * 64;
    src = w1 + (size_t)layer * 131072;
    dst = W1T + (size_t)layer * 131072;
  } else {
    int t = r - 96;
    N = 256;
    k0 = (t & 7) * 64;
    n0 = (t >> 3) * 64;
    src = w2 + (size_t)layer * 131072;
    dst = W2T + (size_t)layer * 131072;
  }
  int K = (r >= 96) ? 512 : 256;

  int tr = threadIdx.x >> 4;
  int tc4 = (threadIdx.x & 15) * 4;
#pragma unroll
  for (int i = 0; i < 4; i++) {
    int kl = i * 16 + tr;
    float4 v = *(const float4*)(src + (size_t)(k0 + kl) * N + n0 + tc4);
    tile[kl][tc4 + 0] = v.x; tile[kl][tc4 + 1] = v.y;
    tile[kl][tc4 + 2] = v.z; tile[kl][tc4 + 3] = v.w;
  }
  __syncthreads();
#pragma unroll
  for (int i = 0; i < 4; i++) {
    int nl = i * 16 + tr;
    bf16x4 o = {(bf16_t)tile[tc4 + 0][nl], (bf16_t)tile[tc4 + 1][nl],
                (bf16_t)tile[tc4 + 2][nl], (bf16_t)tile[tc4 + 3][nl]};
    *(bf16x4*)(dst + (size_t)(n0 + nl) * K + k0 + tc4) = o;
  }
}

// ---------------------------------------------------------------------------
// Single-shot GEMM staging: stage 4 BK=64 k-steps (64 rows x 256 k = 32 KB)
// of a [64 x ldk] row-major slab into LDS via global_load_lds width=16.
// XOR chunk swizzle on the SOURCE side: LDS[st][m][cd] = global chunk
// cd^(m&7) of k-step st, so ds_read_b128 fragment reads are conflict-free.
// ---------------------------------------------------------------------------
__device__ __forceinline__ void stage4(const bf16_t* __restrict__ src,
                                       bf16_t* dst, int tid, int ldk, int kofs) {
#pragma unroll
  for (int st = 0; st < 4; st++) {
#pragma unroll
    for (int u = 0; u < 2; u++) {
      int i = u * 256 + tid;
      int m = i >> 3, cd = i & 7, cs = cd ^ (m & 7);
      const bf16_t* g = src + (size_t)m * ldk + kofs + st * 64 + cs * 8;
      __builtin_amdgcn_global_load_lds(
          (const __attribute__((address_space(1))) unsigned int*)g,
          (__attribute__((address_space(3))) unsigned int*)(dst + st * 4096 + i * 8),
          16, 0, 0);
    }
  }
}

// Compute 4 k-steps (256 k) from staged LDS, barrier-free.
__device__ __forceinline__ void compute4(const bf16_t* As, const bf16_t* Bs,
                                         int mw, int nw, int n16, int quad,
                                         f32x4 (&acc)[2][2]) {
  const int sw = n16 & 7;
#pragma unroll
  for (int st = 0; st < 4; st++) {
#pragma unroll
    for (int ks = 0; ks < 2; ks++) {
      int cd = (ks * 4 + quad) ^ sw;
      bf16x8 a0 = *(const bf16x8*)(As + st * 4096 + (mw + n16) * 64 + cd * 8);
      bf16x8 a1 = *(const bf16x8*)(As + st * 4096 + (mw + 16 + n16) * 64 + cd * 8);
      bf16x8 b0 = *(const bf16x8*)(Bs + st * 4096 + (nw + n16) * 64 + cd * 8);
      bf16x8 b1 = *(const bf16x8*)(Bs + st * 4096 + (nw + 16 + n16) * 64 + cd * 8);
      acc[0][0] = __builtin_amdgcn_mfma_f32_16x16x32_bf16(a0, b0, acc[0][0], 0, 0, 0);
      acc[0][1] = __builtin_amdgcn_mfma_f32_16x16x32_bf16(a0, b1, acc[0][1], 0, 0, 0);
      acc[1][0] = __builtin_amdgcn_mfma_f32_16x16x32_bf16(a1, b0, acc[1][0], 0, 0, 0);
      acc[1][1] = __builtin_amdgcn_mfma_f32_16x16x32_bf16(a1, b1, acc[1][1], 0, 0, 0);
    }
  }
}

// ---------------------------------------------------------------------------
// Generic GEMM (single-shot staging for K=256, two-phase for K=512).
// MODE 0: fp32 residual add. MODE 1: bf16 relu.
// ---------------------------------------------------------------------------
template <int MODE, int N, int K>
__global__ __launch_bounds__(256) void gemm8_kernel(
    const bf16_t* __restrict__ A, const bf16_t* __restrict__ BT,
    const float* __restrict__ bias, const float* __restrict__ resid,
    float* __restrict__ outf, bf16_t* __restrict__ outb) {
  __shared__ __align__(16) bf16_t As[16384];
  __shared__ __align__(16) bf16_t Bs[16384];
  int tid = threadIdx.x;
  int lane = tid & 63;
  int n16 = lane & 15, quad = lane >> 4;
  int w = tid >> 6;
  int m0 = blockIdx.y * 64, n0 = blockIdx.x * 64;
  int mw = (w >> 1) * 32, nw = (w & 1) * 32;
  f32x4 acc[2][2] = {};

  const bf16_t* Arow = A + (size_t)m0 * K;
  const bf16_t* Brow = BT + (size_t)n0 * K;

  stage4(Arow, As, tid, K, 0);
  stage4(Brow, Bs, tid, K, 0);
  __syncthreads();
  compute4(As, Bs, mw, nw, n16, quad, acc);
  if (K == 512) {
    __syncthreads();  // all reads of phase 0 done
    stage4(Arow, As, tid, K, 256);
    stage4(Brow, Bs, tid, K, 256);
    __syncthreads();
    compute4(As, Bs, mw, nw, n16, quad, acc);
  }

  int m_base = m0 + mw;
  int n_base = n0 + nw;
  float bias_v[2];
#pragma unroll
  for (int nt = 0; nt < 2; nt++) bias_v[nt] = bias[n_base + nt * 16 + n16];
#pragma unroll
  for (int mt = 0; mt < 2; mt++)
#pragma unroll
    for (int nt = 0; nt < 2; nt++) {
      int n = n_base + nt * 16 + n16;
#pragma unroll
      for (int r = 0; r < 4; r++) {
        int m = m_base + mt * 16 + quad * 4 + r;
        float val = acc[mt][nt][r] + bias_v[nt];
        if (MODE == 0) {
          size_t idx = (size_t)m * N + n;
          outf[idx] = resid[idx] + val;
        } else {
          outb[(size_t)m * N + n] = (bf16_t)fmaxf(val, 0.0f);
        }
      }
    }
}

// ---------------------------------------------------------------------------
// Fused QKV projection (single-shot staging): grid (12, 128), bx>>2 = Q/K/V.
// ---------------------------------------------------------------------------
__global__ __launch_bounds__(256) void qkv8_kernel(
    const bf16_t* __restrict__ A,
    const bf16_t* __restrict__ WqT, const bf16_t* __restrict__ WkT,
    const bf16_t* __restrict__ WvT,
    const float* __restrict__ bq, const float* __restrict__ bk,
    const float* __restrict__ bv,
    bf16_t* __restrict__ qo, bf16_t* __restrict__ ko,
    bf16_t* __restrict__ vo) {
  __shared__ __align__(16) bf16_t As[16384];
  __shared__ __align__(16) bf16_t Bs[16384];
  int which = blockIdx.x >> 2;
  int nblk = blockIdx.x & 3;
  const bf16_t* BT = (which == 0) ? WqT : (which == 1) ? WkT : WvT;
  const float* bias = (which == 0) ? bq : (which == 1) ? bk : bv;

  int tid = threadIdx.x;
  int lane = tid & 63;
  int n16 = lane & 15, quad = lane >> 4;
  int w = tid >> 6;
  int m0 = blockIdx.y * 64, n0 = nblk * 64;
  int mw = (w >> 1) * 32, nw = (w & 1) * 32;
  f32x4 acc[2][2] = {};

  stage4(A + (size_t)m0 * 256, As, tid, 256, 0);
  stage4(BT + (size_t)n0 * 256, Bs, tid, 256, 0);
  __syncthreads();
  compute4(As, Bs, mw, nw, n16, quad, acc);

  int m_base = m0 + mw;
  int n_base = n0 + nw;
  float bias_v[2];
#pragma unroll
  for (int nt = 0; nt < 2; nt++) bias_v[nt] = bias[n_base + nt * 16 + n16];

#pragma unroll
  for (int mt = 0; mt < 2; mt++)
#pragma unroll
    for (int nt = 0; nt < 2; nt++) {
      int n = n_base + nt * 16 + n16;
      int hh = n >> 5, dk = n & 31;
      if (which == 2) {
        int s0 = m_base + mt * 16 + quad * 4;
        int bb = s0 >> 11, ss0 = s0 & 2047;
        bf16x4 o;
#pragma unroll
        for (int r = 0; r < 4; r++) o[r] = (bf16_t)(acc[mt][nt][r] + bias_v[nt]);
        *(bf16x4*)(vo + ((size_t)(bb * NH + hh) * DK + dk) * SEQ + ss0) = o;
      } else {
        bf16_t* dst = (which == 0) ? qo : ko;
        float sc = (which == 0) ? QK_SCALE_LOG2 : 1.0f;
#pragma unroll
        for (int r = 0; r < 4; r++) {
          int m = m_base + mt * 16 + quad * 4 + r;
          int bb = m >> 11, ss = m & 2047;
          dst[((size_t)(bb * NH + hh) * SEQ + ss) * DK + dk] =
              (bf16_t)((acc[mt][nt][r] + bias_v[nt]) * sc);
        }
      }
    }
}

// ---------------------------------------------------------------------------
// Flash attention v7: 32 q/wave, S^T score trick, ones-MFMA row-sums,
// double-buffered P in LDS, and EXPLICIT register prefetch of next tile's
// K/V fragments (issued before the current tile's exp/LDS chain so the
// ~200-600 cyc global latency hides under a full tile of compute).
// grid (32 bh, 32 qblk), 128 threads. No barriers, no loop cross-lane ops.
// ---------------------------------------------------------------------------
__global__ __launch_bounds__(128) void flash7_kernel(
    const bf16_t* __restrict__ Q, const bf16_t* __restrict__ K,
    const bf16_t* __restrict__ VT, bf16_t* __restrict__ OB) {
  __shared__ __align__(16) bf16_t Plds[2][2][32][72];  // [buf][wave][q][key]
  int bh = blockIdx.x;
  int q0 = blockIdx.y * 64;
  int w = threadIdx.x >> 6;
  int lane = threadIdx.x & 63;
  int n16 = lane & 15;
  int quad = lane >> 4;

  const bf16_t* Qb = Q + (size_t)bh * SEQ * DK;
  const bf16_t* Kb = K + (size_t)bh * SEQ * DK;
  const bf16_t* Vb = VT + (size_t)bh * DK * SEQ;
  int qr0 = q0 + w * 32;

  bf16x8 qfrag[2];
#pragma unroll
  for (int qg = 0; qg < 2; qg++)
    qfrag[qg] = *(const bf16x8*)(Qb + (size_t)(qr0 + qg * 16 + n16) * DK + quad * 8);

  bf16_t one = (bf16_t)1.0f;
  bf16x8 ones = {one, one, one, one, one, one, one, one};

  f32x4 oacc[2][2] = {};
  f32x4 lacc[2] = {};

  // prologue: load tile 0 fragments
  bf16x8 kfc[4], vfc[2][2];
#pragma unroll
  for (int t = 0; t < 4; t++)
    kfc[t] = *(const bf16x8*)(Kb + (size_t)(t * 16 + n16) * DK + quad * 8);
#pragma unroll
  for (int c = 0; c < 2; c++) {
    vfc[c][0] = *(const bf16x8*)(Vb + (size_t)n16 * SEQ + c * 32 + quad * 8);
    vfc[c][1] = *(const bf16x8*)(Vb + (size_t)(16 + n16) * SEQ + c * 32 + quad * 8);
  }

#pragma unroll 2
  for (int kb0 = 0; kb0 < SEQ; kb0 += 64) {
    int buf = (kb0 >> 6) & 1;
    int nb = kb0 + 64;
    bool has_next = nb < SEQ;
    // prefetch next tile (independent of everything below)
    bf16x8 kfn[4], vfn[2][2];
    if (has_next) {
#pragma unroll
      for (int t = 0; t < 4; t++)
        kfn[t] = *(const bf16x8*)(Kb + (size_t)(nb + t * 16 + n16) * DK + quad * 8);
#pragma unroll
      for (int c = 0; c < 2; c++) {
        vfn[c][0] = *(const bf16x8*)(Vb + (size_t)n16 * SEQ + nb + c * 32 + quad * 8);
        vfn[c][1] = *(const bf16x8*)(Vb + (size_t)(16 + n16) * SEQ + nb + c * 32 + quad * 8);
      }
    }
    // scores (S^T): D[key=quad*4+r][q=n16]; exp; packed b64 P stores
#pragma unroll
    for (int qg = 0; qg < 2; qg++) {
#pragma unroll
      for (int t = 0; t < 4; t++) {
        f32x4 sc = __builtin_amdgcn_mfma_f32_16x16x32_bf16(
            kfc[t], qfrag[qg], (f32x4){0.f, 0.f, 0.f, 0.f}, 0, 0, 0);
        bf16x4 pf;
#pragma unroll
        for (int r = 0; r < 4; r++) pf[r] = (bf16_t)FAST_EXP2(sc[r]);
        *(bf16x4*)&Plds[buf][w][qg * 16 + n16][t * 16 + quad * 4] = pf;
      }
    }
    // PV + l (ones-MFMA): A = P[q][key] b128 reads, B = V / ones
#pragma unroll
    for (int qg = 0; qg < 2; qg++)
#pragma unroll
      for (int c = 0; c < 2; c++) {
        bf16x8 pf8 = *(const bf16x8*)&Plds[buf][w][qg * 16 + n16][c * 32 + quad * 8];
        lacc[qg] = __builtin_amdgcn_mfma_f32_16x16x32_bf16(pf8, ones, lacc[qg], 0, 0, 0);
        oacc[qg][0] = __builtin_amdgcn_mfma_f32_16x16x32_bf16(pf8, vfc[c][0], oacc[qg][0], 0, 0, 0);
        oacc[qg][1] = __builtin_amdgcn_mfma_f32_16x16x32_bf16(pf8, vfc[c][1], oacc[qg][1], 0, 0, 0);
      }
    // rotate prefetch buffers
    if (has_next) {
#pragma unroll
      for (int t = 0; t < 4; t++) kfc[t] = kfn[t];
#pragma unroll
      for (int c = 0; c < 2; c++) {
        vfc[c][0] = vfn[c][0];
        vfc[c][1] = vfn[c][1];
      }
    }
  }

  int bb = bh >> 3, hh = bh & 7;
#pragma unroll
  for (int qg = 0; qg < 2; qg++)
#pragma unroll
    for (int r = 0; r < 4; r++) {
      float linv = 1.0f / lacc[qg][r];
      int row = qr0 + qg * 16 + quad * 4 + r;
      bf16_t* op = OB + ((size_t)(bb * SEQ + row)) * DIM + hh * DK;
      op[n16] = (bf16_t)(oacc[qg][0][r] * linv);
      op[16 + n16] = (bf16_t)(oacc[qg][1][r] * linv);
    }
}

// ---------------------------------------------------------------------------
extern "C" void kernel_launch(void* const* d_in, const int* in_sizes, int n_in,
                              void* d_out, int out_size, void* d_ws, size_t ws_size,
                              hipStream_t stream) {
  const float* x     = (const float*)d_in[0];
  const float* ln0_s = (const float*)d_in[1];
  const float* ln0_b = (const float*)d_in[2];
  const float* ln1_s = (const float*)d_in[3];
  const float* ln1_b = (const float*)d_in[4];
  const float* ln2_s = (const float*)d_in[5];
  const float* ln2_b = (const float*)d_in[6];
  const float* wq = (const float*)d_in[7];
  const float* bq = (const float*)d_in[8];
  const float* wk = (const float*)d_in[9];
  const float* bk = (const float*)d_in[10];
  const float* wv = (const float*)d_in[11];
  const float* bv = (const float*)d_in[12];
  const float* wo = (const float*)d_in[13];
  const float* bo = (const float*)d_in[14];
  const float* w1 = (const float*)d_in[15];
  const float* b1 = (const float*)d_in[16];
  const float* w2 = (const float*)d_in[17];
  const float* b2 = (const float*)d_in[18];

  float* out = (float*)d_out;  // h (fp32 residual stream) lives here
  const size_t ACT = (size_t)8192 * DIM;  // 2,097,152

  bf16_t* wsb = (bf16_t*)d_ws;
  bf16_t* x2b = wsb;                 // ACT
  bf16_t* obf = x2b + ACT;           // ACT
  bf16_t* qbf = obf + ACT;           // ACT
  bf16_t* kbf = qbf + ACT;           // ACT
  bf16_t* vbf = kbf + ACT;           // ACT (transposed [B,H,DK,S])
  bf16_t* h1b = vbf + ACT;           // 2*ACT (8192 x 512)
  bf16_t* WqT = h1b + 2 * ACT;       // 4 x 65536
  bf16_t* WkT = WqT + 4 * 65536;
  bf16_t* WvT = WkT + 4 * 65536;
  bf16_t* WoT = WvT + 4 * 65536;
  bf16_t* W1T = WoT + 4 * 65536;     // 4 x 131072
  bf16_t* W2T = W1T + 4 * 131072;    // 4 x 131072

  dim3 blk(256);
  dim3 blkF(128);
  dim3 gLN(2048);
  dim3 gG256(4, 128);
  dim3 gG512(8, 128);
  dim3 gQKV(12, 128);
  dim3 gAtt(32, 32);

  wtrans_all_kernel<<<dim3(512), blk, 0, stream>>>(wq, wk, wv, wo, w1, w2,
                                                   WqT, WkT, WvT, WoT, W1T, W2T);

  // h = LN(x, ln0) -> fp32 d_out
  ln_kernel<0><<<gLN, blk, 0, stream>>>(x, ln0_s, ln0_b, out, nullptr);

  for (int l = 0; l < 4; l++) {
    bf16_t* WqTl = WqT + (size_t)l * 65536;
    bf16_t* WkTl = WkT + (size_t)l * 65536;
    bf16_t* WvTl = WvT + (size_t)l * 65536;
    bf16_t* WoTl = WoT + (size_t)l * 65536;
    bf16_t* W1Tl = W1T + (size_t)l * 131072;
    bf16_t* W2Tl = W2T + (size_t)l * 131072;

    // x2 = LN(h, ln1) -> bf16
    ln_kernel<1><<<gLN, blk, 0, stream>>>(out, ln1_s + l * DIM, ln1_b + l * DIM, nullptr, x2b);
    // fused q,k,v projections (single-shot staged GEMM)
    qkv8_kernel<<<gQKV, blk, 0, stream>>>(x2b, WqTl, WkTl, WvTl,
                                          bq + l * DIM, bk + l * DIM, bv + l * DIM,
                                          qbf, kbf, vbf);
    // attention
    flash7_kernel<<<gAtt, blkF, 0, stream>>>(qbf, kbf, vbf, obf);
    // h = h + o @ Wo + bo
    gemm8_kernel<0, 256, 256><<<gG256, blk, 0, stream>>>(obf, WoTl, bo + l * DIM, out, out, nullptr);
    // x2 = LN(h, ln2) -> bf16
    ln_kernel<1><<<gLN, blk, 0, stream>>>(out, ln2_s + l * DIM, ln2_b + l * DIM, nullptr, x2b);
    // h1 = relu(x2 @ W1 + b1) -> bf16
    gemm8_kernel<1, 512, 256><<<gG512, blk, 0, stream>>>(x2b, W1Tl, b1 + l * FF, nullptr, nullptr, h1b);
    // h = h + h1 @ W2 + b2
    gemm8_kernel<0, 256, 512><<<gG256, blk, 0, stream>>>(h1b, W2Tl, b2 + l * DIM, out, out, nullptr);
  }
}